// Round 10
// baseline (184.773 us; speedup 1.0000x reference)
//
#include <hip/hip_runtime.h>

// RecallK via bf16 hi/lo split on matrix cores.
// dot(x_i,x_j) ~= hi.hi + lo.hi + hi.lo  (lo.lo dropped: ~2e-5 distance noise,
// ~0.2 expected argmin flips vs 3.2-flip threshold budget).
// argmin_j (sq_j - 2*dot) per row == argmin of ref distmat (row-constant sq_i dropped).
// R10: finish de-lockstep. R9 (2 blocks/CU x 8 waves) = MfmaUtil 58%; gap == epilogue
// VALU (1024 cyc/SIMD/tile) serialized with MFMA because co-resident waves share
// barrier phases. Now 4-wave blocks, 32-col tiles, 32 KB LDS -> 4 independent
// blocks/CU (16 waves/CU): each SIMD's 4 waves come from 4 different blocks ->
// epilogue of one overlaps MFMA of another. Diagonal check hoisted: 32-aligned tiles
// -> diag only when jb == rowlo (wave-uniform), 63/64 tiles run check-free path.
// P16 layout (A and B frags of mfma_f32_16x16x32_bf16 read lane-linear 16B chunks):
//   chunk(g16,ks,l) = (g16*4+ks)*64+l  holds  X[g16*16+(l&15)][ks*32+(l>>4)*8 .. +8]
//   same permutation for A and B -> any within-k shuffle cancels in A.B

typedef __bf16 bf16x8 __attribute__((ext_vector_type(8)));
typedef float f32x4 __attribute__((ext_vector_type(4)));

#define NN 16384
#define MFMA16(A, B, C) __builtin_amdgcn_mfma_f32_16x16x32_bf16(A, B, C, 0, 0, 0)
#define GLDS(gsrc, ldst)                                                              \
  __builtin_amdgcn_global_load_lds((const __attribute__((address_space(1))) void*)(gsrc), \
                                   (__attribute__((address_space(3))) void*)(ldst), 16, 0, 0)

// --- per-row squared norms, exact fp32 (one wave per row) ---
__global__ __launch_bounds__(256) void sq_kernel(const float* __restrict__ feat,
                                                 float* __restrict__ sq) {
  int gid = blockIdx.x * 256 + threadIdx.x;
  int row = gid >> 6;
  int lane = threadIdx.x & 63;
  float2 v = reinterpret_cast<const float2*>(feat + (size_t)row * 128)[lane];
  float s = v.x * v.x + v.y * v.y;
#pragma unroll
  for (int off = 32; off > 0; off >>= 1) s += __shfl_xor(s, off, 64);
  if (lane == 0) sq[row] = s;
}

// --- fp32 -> (hi,lo) bf16 banks in 16-row-group MFMA-chunk order ---
__global__ __launch_bounds__(256) void convert_kernel(const float* __restrict__ feat,
                                                      bf16x8* __restrict__ Ph,
                                                      bf16x8* __restrict__ Pl) {
  int chunk = blockIdx.x * 256 + threadIdx.x;  // 262144 chunks
  int l = chunk & 63;
  int ks = (chunk >> 6) & 3;
  int g = chunk >> 8;                          // 0..1023 (16-row groups)
  int row = g * 16 + (l & 15);
  int k0 = ks * 32 + (l >> 4) * 8;
  const float4* s = reinterpret_cast<const float4*>(feat + (size_t)row * 128 + k0);
  float4 v0 = s[0], v1 = s[1];
  float xs[8] = {v0.x, v0.y, v0.z, v0.w, v1.x, v1.y, v1.z, v1.w};
  bf16x8 hv, lv;
#pragma unroll
  for (int e = 0; e < 8; ++e) {
    float x = xs[e];
    __bf16 h = (__bf16)x;
    hv[e] = h;
    lv[e] = (__bf16)(x - (float)h);
  }
  Ph[chunk] = hv;
  Pl[chunk] = lv;
}

// --- main: 1024 blocks (128 panels x 8 slices), 4 waves x 32 rows, 32-col tiles ---
__global__ __launch_bounds__(256, 4) void nn_mfma(const bf16x8* __restrict__ Ph,
                                                  const bf16x8* __restrict__ Pl,
                                                  const float* __restrict__ sq,
                                                  float* __restrict__ bestD,
                                                  int* __restrict__ bestI) {
  __shared__ bf16x8 BhL[2][512];  // [buf][cg*256 + ks*64 + lane]  2 x 8 KB
  __shared__ bf16x8 BlL[2][512];  // 2 x 8 KB  -> total 32 KB -> 4 blocks/CU
  const int bid = blockIdx.x;
  const int slice = bid & 7;       // 2048-col slice; one per XCD (1 MB hi+lo, L2-fit)
  const int panel = bid >> 3;      // 0..127 row-panels of 128 rows
  const int tid = threadIdx.x;
  const int w = tid >> 6;          // wave 0..3
  const int lane = tid & 63;
  const int lq = lane >> 4;        // row-quad selector in C layout
  const int lc = lane & 15;        // col-in-group

  // A: two 16-row groups (32 rows x K=128, hi+lo): 16 frags = 64 VGPR
  bf16x8 Ah0[4], Al0[4], Ah1[4], Al1[4];
  {
    int gA = panel * 8 + w * 2;
#pragma unroll
    for (int ks = 0; ks < 4; ++ks) {
      Ah0[ks] = Ph[(gA * 4 + ks) * 64 + lane];
      Al0[ks] = Pl[(gA * 4 + ks) * 64 + lane];
      Ah1[ks] = Ph[((gA + 1) * 4 + ks) * 64 + lane];
      Al1[ks] = Pl[((gA + 1) * 4 + ks) * 64 + lane];
    }
  }

  // stage one 32-col B tile (hi+lo) into buffer `nbuf`: 16 GLDS, 4 per wave.
  // wave w: bank = w&1, col-16-group cgi = w>>1
  auto stage = [&](int nbuf, int tt) {
    const int cgi = w >> 1;
    const int gcol = slice * 128 + tt * 2 + cgi;
    const bf16x8* src = (w & 1) ? Pl : Ph;
    bf16x8* dst = ((w & 1) ? &BlL[nbuf][0] : &BhL[nbuf][0]) + cgi * 256;
#pragma unroll
    for (int ks = 0; ks < 4; ++ks) {
      size_t srcoff = ((size_t)((gcol * 4 + ks) * 64 + lane)) * 16;
      GLDS((const char*)src + srcoff, dst + ks * 64);
    }
  };

  float best0[4], best1[4];
  int bidx0[4], bidx1[4];
#pragma unroll
  for (int r = 0; r < 4; ++r) {
    best0[r] = 3.4e38f; best1[r] = 3.4e38f;
    bidx0[r] = 0; bidx1[r] = 0;
  }

  stage(0, 0);
  __syncthreads();  // full fence: stage complete + all waves synced

  int buf = 0;
  const int rowlo = panel * 128 + w * 32;  // this wave's 32 rows (32-aligned)
  const int ig0 = rowlo + lq * 4;          // + r = rowgroup0 rows; +16 = rowgroup1

  for (int t = 0; t < 64; ++t) {
    const int jb = slice * 2048 + t * 32;
    float sqc[2];
#pragma unroll
    for (int cg = 0; cg < 2; ++cg) sqc[cg] = sq[jb + cg * 16 + lc];  // before stage:
    if (t < 63) stage(buf ^ 1, t + 1);                               // counted vmcnt wait

    // per cg: 2 ds_reads feed 6 MFMA (2 rowgroups x 3 terms)
#pragma unroll
    for (int cg = 0; cg < 2; ++cg) {
      f32x4 a0 = {}, a1 = {};
#pragma unroll
      for (int ks = 0; ks < 4; ++ks) {
        bf16x8 bh = BhL[buf][cg * 256 + ks * 64 + lane];
        bf16x8 bl = BlL[buf][cg * 256 + ks * 64 + lane];
        a0 = MFMA16(Ah0[ks], bh, a0);
        a0 = MFMA16(Al0[ks], bh, a0);
        a0 = MFMA16(Ah0[ks], bl, a0);
        a1 = MFMA16(Ah1[ks], bh, a1);
        a1 = MFMA16(Al1[ks], bh, a1);
        a1 = MFMA16(Ah1[ks], bl, a1);
      }
      // epilogue: d = sq_j - 2*dot; ascending cg then t, strict < = first-min.
      // 32-aligned tiles: diagonal only possible when jb == rowlo (wave-uniform).
      const int j = jb + cg * 16 + lc;
      if (jb != rowlo) {
#pragma unroll
        for (int r = 0; r < 4; ++r) {
          float d0 = fmaf(-2.0f, a0[r], sqc[cg]);
          if (d0 < best0[r]) { best0[r] = d0; bidx0[r] = j; }
          float d1 = fmaf(-2.0f, a1[r], sqc[cg]);
          if (d1 < best1[r]) { best1[r] = d1; bidx1[r] = j; }
        }
      } else {
#pragma unroll
        for (int r = 0; r < 4; ++r) {
          float d0 = fmaf(-2.0f, a0[r], sqc[cg]);
          if (j != ig0 + r && d0 < best0[r]) { best0[r] = d0; bidx0[r] = j; }
          float d1 = fmaf(-2.0f, a1[r], sqc[cg]);
          if (j != ig0 + 16 + r && d1 < best1[r]) { best1[r] = d1; bidx1[r] = j; }
        }
      }
    }

    __syncthreads();  // drains my stage (vmcnt 0) + all waves done reading buf
    buf ^= 1;
  }

  // cross-lane argmin over the 16 col-lanes sharing each row; lex (d,j) = first-min
#pragma unroll
  for (int r = 0; r < 4; ++r) {
    float d0 = best0[r], d1 = best1[r];
    int i0 = bidx0[r], i1 = bidx1[r];
#pragma unroll
    for (int off = 1; off < 16; off <<= 1) {
      float od = __shfl_xor(d0, off); int oi = __shfl_xor(i0, off);
      if (od < d0 || (od == d0 && oi < i0)) { d0 = od; i0 = oi; }
      od = __shfl_xor(d1, off); oi = __shfl_xor(i1, off);
      if (od < d1 || (od == d1 && oi < i1)) { d1 = od; i1 = oi; }
    }
    if (lc == 0) {  // rows are wave/lane-quad exclusive
      bestD[slice * NN + ig0 + r] = d0;
      bestI[slice * NN + ig0 + r] = i0;
      bestD[slice * NN + ig0 + 16 + r] = d1;
      bestI[slice * NN + ig0 + 16 + r] = i1;
    }
  }
}

// --- merge 8 slices per row, count label matches ---
__global__ __launch_bounds__(256) void combine_kernel(const float* __restrict__ bestD,
                                                      const int* __restrict__ bestI,
                                                      const int* __restrict__ labels,
                                                      int* __restrict__ count) {
  int r = blockIdx.x * 256 + threadIdx.x;
  float d = bestD[r];
  int i = bestI[r];
#pragma unroll
  for (int s = 1; s < 8; ++s) {
    float ds = bestD[s * NN + r];
    int is = bestI[s * NN + r];
    if (ds < d || (ds == d && is < i)) { d = ds; i = is; }
  }
  bool match = (labels[i] == labels[r]);
  unsigned long long mb = __ballot(match);
  if ((threadIdx.x & 63) == 0) atomicAdd(count, (int)__popcll(mb));
}

__global__ void finalize_kernel(const int* __restrict__ count, float* __restrict__ out) {
  out[0] = (float)(*count) * (1.0f / 16384.0f);
}

extern "C" void kernel_launch(void* const* d_in, const int* in_sizes, int n_in,
                              void* d_out, int out_size, void* d_ws, size_t ws_size,
                              hipStream_t stream) {
  const float* feat = (const float*)d_in[0];
  const int* labels = (const int*)d_in[1];
  float* out = (float*)d_out;
  char* ws = (char*)d_ws;

  int* count = (int*)ws;                              // 4 B
  float* sq = (float*)(ws + 1024);                    // 64 KB
  float* bestD = (float*)(ws + (1 << 19));            // 8*N floats = 512 KB
  int* bestI = (int*)(ws + (1 << 20));                // 8*N ints  = 512 KB
  bf16x8* Ph = (bf16x8*)(ws + (2 << 20));             // 4 MB
  bf16x8* Pl = (bf16x8*)(ws + (6 << 20));             // 4 MB   (total 10 MB)

  hipMemsetAsync(count, 0, sizeof(int), stream);
  sq_kernel<<<NN / 4, 256, 0, stream>>>(feat, sq);
  convert_kernel<<<1024, 256, 0, stream>>>(feat, Ph, Pl);
  nn_mfma<<<1024, 256, 0, stream>>>(Ph, Pl, sq, bestD, bestI);
  combine_kernel<<<NN / 256, 256, 0, stream>>>(bestD, bestI, labels, count);
  finalize_kernel<<<1, 1, 0, stream>>>(count, out);
}